// Round 5
// baseline (328.992 us; speedup 1.0000x reference)
//
#include <hip/hip_runtime.h>

// ---------------------------------------------------------------------------
// DensityMatrixMLP: out[b] = (L Lt) / trace(L Lt),  L = tril(relu(x@W1+b1)@W2+b2)
// B=131072, IN=256, HID=128, TRIL=136, D=16.
//
// R4 post-mortem: time fits waves x serial-chain / ~13 resident; the chain is
// ~116 latency-exposed weight loads/tile (100KB working set >> 32KB L1, every
// wave re-walks it). R5: one 1024-thread block per CU; pw1 (64KB) staged in
// LDS once per block -> B-frags via ds_read_b128 (120cy, MFMA-hidden). pw2
// stays global (VMEM pipe) and overlaps GEMM1 (LDS pipe) across 16 waves.
// 2 tiles/wave, x-tile prefetch across tiles, ONE barrier total.
// LDS: 64KB pw1 + 16 waves x 5120B chunks = 144KB (dynamic, FuncSetAttribute).
// ---------------------------------------------------------------------------

typedef _Float16 h8 __attribute__((ext_vector_type(8)));
typedef float    f4 __attribute__((ext_vector_type(4)));
typedef int      i2 __attribute__((ext_vector_type(2)));

#define BATCH_N 131072
#define IN_DIM  256
#define HID     128
#define TRILN   136
#define NT1     8        // 128/16 n-tiles, GEMM1
#define KS1     8        // 256/32 k-steps, GEMM1
#define NT2     9        // ceil(136/16) n-tiles, GEMM2 (padded with zeros)
#define KS2     4        // 128/32 k-steps, GEMM2
#define HSTR    136      // h row stride (halves): 272B, 16B-aligned rows
#define LVSTR   160      // padded-tril row stride (halves): rows 4-half aligned
#define CHUNKH  (16*LVSTR)          // per-wave LDS chunk, halves (5120 B)
#define PW1_N   (KS1*NT1*64*8)      // 32768 halves = 64 KB
#define PW2_N   (KS2*NT2*64*8)      // 18432 halves = 36 KB
#define NWAVE   16
#define ROWS_PER_BLOCK (NWAVE*32)   // 512 (2 tiles of 16 per wave)
#define LDS_BYTES (PW1_N*2 + NWAVE*CHUNKH*2)   // 65536 + 81920 = 147456

// offset (halves) of tril row i inside a batch row's LVSTR region
__device__ __forceinline__ int rowoff(int i) {
    int g = i >> 2;
    return 4 * (g + 1) * (2 * g + (i & 3));   // 0,4,8,...,144
}

// ---------------------------------------------------------------------------
// Prelude: pack W1/W2 into MFMA B-fragment order, fp16.
// B-frag of mfma_16x16x32_f16: lane holds B[k=(lane>>4)*8+j][n=lane&15], j=0..7.
// ---------------------------------------------------------------------------
__global__ void pack_weights(const float* __restrict__ W1,
                             const float* __restrict__ W2,
                             _Float16* __restrict__ pw1,
                             _Float16* __restrict__ pw2) {
    int gid = blockIdx.x * blockDim.x + threadIdx.x;
    if (gid < PW1_N) {
        int j = gid & 7, l = (gid >> 3) & 63, f = gid >> 9;
        int ks = f >> 3, nt = f & 7;
        int k = ks * 32 + (l >> 4) * 8 + j;
        int n = nt * 16 + (l & 15);
        pw1[gid] = (_Float16)W1[k * HID + n];
    } else if (gid < PW1_N + PW2_N) {
        int g = gid - PW1_N;
        int j = g & 7, l = (g >> 3) & 63, f = g >> 9;
        int ks = f / NT2, nt = f - ks * NT2;
        int k = ks * 32 + (l >> 4) * 8 + j;
        int col = nt * 16 + (l & 15);
        pw2[g] = (col < TRILN) ? (_Float16)W2[k * TRILN + col] : (_Float16)0.0f;
    }
}

__device__ __forceinline__ h8 cvt_h8(f4 lo, f4 hi) {
    h8 r;
    r[0] = (_Float16)lo[0]; r[1] = (_Float16)lo[1];
    r[2] = (_Float16)lo[2]; r[3] = (_Float16)lo[3];
    r[4] = (_Float16)hi[0]; r[5] = (_Float16)hi[1];
    r[6] = (_Float16)hi[2]; r[7] = (_Float16)hi[3];
    return r;
}

// ---------------------------------------------------------------------------
// Fused kernel: 1024 threads (16 waves), 512 batch rows/block, grid=256
// (1 block/CU). pw1 in LDS (shared, read-only after the single barrier);
// everything else wave-private.
// ---------------------------------------------------------------------------
__global__ __launch_bounds__(1024, 4) void fused_mlp(
        const float* __restrict__ x, const float* __restrict__ b1,
        const float* __restrict__ b2, const _Float16* __restrict__ pw1,
        const _Float16* __restrict__ pw2, float* __restrict__ out) {
    extern __shared__ _Float16 smem[];   // LDS_BYTES, set via FuncSetAttribute

    const int tid  = threadIdx.x;
    const int w    = tid >> 6;
    const int lane = tid & 63;
    const int q    = lane >> 4;
    const int lm   = lane & 15;
    const int rw0  = blockIdx.x * ROWS_PER_BLOCK + w * 32;  // this wave's 32 rows

    const _Float16* pwl = smem;                       // pw1 mirror, 32768 halves
    _Float16* chunk = smem + PW1_N + w * CHUNKH;      // wave-private 2560 halves
    _Float16* hbuf = chunk;                           // [16][HSTR]
    _Float16* lv   = chunk;                           // [16][LVSTR] (overlaid)

    // ---- x prefetch for tile 0 (issued before the staging loads) ----
    const float* xp = x + (size_t)(rw0 + lm) * IN_DIM + q * 8;
    f4 xa[2 * KS1];
    #pragma unroll
    for (int ks = 0; ks < KS1; ++ks) {
        xa[2 * ks]     = *(const f4*)(xp + ks * 32);
        xa[2 * ks + 1] = *(const f4*)(xp + ks * 32 + 4);
    }

    // ---- cooperative pw1 -> LDS (64KB; 4 x dwordx4 per thread) ----
    {
        const f4* src = (const f4*)pw1;
        f4* dst = (f4*)smem;
        #pragma unroll
        for (int k = 0; k < 4; ++k) {
            int i = k * 1024 + tid;
            dst[i] = src[i];
        }
    }
    __syncthreads();   // the only barrier

    // lane-invariant epilogue tables (hoisted out of the tile loop)
    int voff[NT2];
    bool vok[NT2];
    #pragma unroll
    for (int nt = 0; nt < NT2; ++nt) {
        int c = nt * 16 + lm;
        vok[nt] = (c < TRILN);
        int cc = vok[nt] ? c : 0;
        int i = (int)((sqrtf(8.0f * (float)cc + 1.0f) - 1.0f) * 0.5f);
        int k = cc - (i * (i + 1)) / 2;
        voff[nt] = rowoff(i) + k;
    }
    int msk[4];
    {
        int n = lm - q * 8 + 1;
        #pragma unroll
        for (int p = 0; p < 4; ++p) {
            int c2 = n - 2 * p; c2 = c2 < 0 ? 0 : (c2 > 2 ? 2 : c2);
            msk[p] = (c2 == 2) ? ~0 : ((c2 == 1) ? 0xFFFF : 0);
        }
    }
    const int ro_lm = rowoff(lm);
    const f4 zero = (f4){0.f, 0.f, 0.f, 0.f};
    const int outcol = q * 64 + lm;

    #pragma unroll
    for (int t = 0; t < 2; ++t) {
        const int r0 = rw0 + t * 16;   // first batch row of this tile

        // convert the prefetched x to fp16 frags, then immediately issue the
        // next tile's x loads (hidden under this whole tile's work)
        h8 xh[KS1];
        #pragma unroll
        for (int ks = 0; ks < KS1; ++ks)
            xh[ks] = cvt_h8(xa[2 * ks], xa[2 * ks + 1]);
        if (t == 0) {
            const float* xp1 = xp + (size_t)16 * IN_DIM;
            #pragma unroll
            for (int ks = 0; ks < KS1; ++ks) {
                xa[2 * ks]     = *(const f4*)(xp1 + ks * 32);
                xa[2 * ks + 1] = *(const f4*)(xp1 + ks * 32 + 4);
            }
        }

        // ---------------- GEMM1: h = relu(x @ W1 + b1), B-frags from LDS ----
        f4 acc1[NT1];
        #pragma unroll
        for (int nt = 0; nt < NT1; ++nt) acc1[nt] = (f4){0.f, 0.f, 0.f, 0.f};

        #pragma unroll
        for (int ks = 0; ks < KS1; ++ks) {
            #pragma unroll
            for (int nt = 0; nt < NT1; ++nt) {
                h8 bf = *(const h8*)(pwl + ((ks * NT1 + nt) * 64 + lane) * 8);
                acc1[nt] = __builtin_amdgcn_mfma_f32_16x16x32_f16(xh[ks], bf, acc1[nt], 0, 0, 0);
            }
        }

        // bias + relu + h -> private LDS
        {
            float b1v;
            #pragma unroll
            for (int nt = 0; nt < NT1; ++nt) {
                b1v = b1[nt * 16 + lm];
                #pragma unroll
                for (int r = 0; r < 4; ++r) {
                    float hv = fmaxf(acc1[nt][r] + b1v, 0.f);
                    hbuf[(q * 4 + r) * HSTR + nt * 16 + lm] = (_Float16)hv;  // C-layout
                }
            }
        }

        // ---------------- GEMM2: v = h @ W2 + b2 (pw2 from global/L2) -------
        f4 acc2[NT2];
        #pragma unroll
        for (int nt = 0; nt < NT2; ++nt) acc2[nt] = (f4){0.f, 0.f, 0.f, 0.f};

        h8 ha[KS2];
        #pragma unroll
        for (int ks = 0; ks < KS2; ++ks)
            ha[ks] = *(const h8*)(hbuf + lm * HSTR + ks * 32 + q * 8);

        #pragma unroll
        for (int nt = 0; nt < NT2; ++nt) {
            #pragma unroll
            for (int ks = 0; ks < KS2; ++ks) {
                h8 bf = *(const h8*)(pw2 + ((ks * NT2 + nt) * 64 + lane) * 8);
                acc2[nt] = __builtin_amdgcn_mfma_f32_16x16x32_f16(ha[ks], bf, acc2[nt], 0, 0, 0);
            }
        }

        float b2v[NT2];
        #pragma unroll
        for (int nt = 0; nt < NT2; ++nt) {
            int col = nt * 16 + lm;
            b2v[nt] = (col < TRILN) ? b2[col] : 0.f;
        }

        // trace from registers; reduce across the 16 lanes of each row
        float rinv[4];
        {
            float ps[4] = {0.f, 0.f, 0.f, 0.f};
            #pragma unroll
            for (int nt = 0; nt < NT2; ++nt)
                #pragma unroll
                for (int r = 0; r < 4; ++r) {
                    float v = acc2[nt][r] + b2v[nt];   // cols>=136 contribute 0
                    ps[r] += v * v;
                }
            #pragma unroll
            for (int r = 0; r < 4; ++r) {
                float s = ps[r];
                s += __shfl_xor(s, 1);
                s += __shfl_xor(s, 2);
                s += __shfl_xor(s, 4);
                s += __shfl_xor(s, 8);
                rinv[r] = 1.0f / s;
            }
        }

        // scatter v (fp16) into padded-tril layout (wave-private region)
        #pragma unroll
        for (int r = 0; r < 4; ++r) {
            int base = (q * 4 + r) * LVSTR;
            #pragma unroll
            for (int nt = 0; nt < NT2; ++nt)
                if (vok[nt])
                    lv[base + voff[nt]] = (_Float16)(acc2[nt][r] + b2v[nt]);
        }

        // ---------------- LL^T via MFMA: A-frag == B-frag identity ----------
        #pragma unroll
        for (int tq = 0; tq < 4; ++tq)
            #pragma unroll
            for (int r4 = 0; r4 < 4; ++r4) {
                int tt = tq * 4 + r4;
                const _Float16* rp = lv + tt * LVSTR + ro_lm + q * 8;
                i2 lo = *(const i2*)rp;
                i2 hi = *(const i2*)(rp + 4);
                h8 frag;
                ((i2*)&frag)[0] = (i2){lo.x & msk[0], lo.y & msk[1]};
                ((i2*)&frag)[1] = (i2){hi.x & msk[2], hi.y & msk[3]};
                f4 d = __builtin_amdgcn_mfma_f32_16x16x32_f16(frag, frag, zero, 0, 0, 0);
                float riv = __uint_as_float(
                    __builtin_amdgcn_readlane(__float_as_uint(rinv[r4]), tq * 16));
                float* op = out + (size_t)(r0 + tt) * 256 + outcol;
                #pragma unroll
                for (int sr = 0; sr < 4; ++sr)
                    op[sr * 16] = d[sr] * riv;   // 4x64B sectors per instr
            }
    }
}

extern "C" void kernel_launch(void* const* d_in, const int* in_sizes, int n_in,
                              void* d_out, int out_size, void* d_ws, size_t ws_size,
                              hipStream_t stream) {
    const float* x  = (const float*)d_in[0];
    const float* W1 = (const float*)d_in[1];
    const float* b1 = (const float*)d_in[2];
    const float* W2 = (const float*)d_in[3];
    const float* b2 = (const float*)d_in[4];
    float* out = (float*)d_out;

    _Float16* pw1 = (_Float16*)d_ws;            // 64 KB
    _Float16* pw2 = pw1 + PW1_N;                // 36 KB  (needs ws_size >= 100 KB)

    // allow 144KB dynamic LDS (host-side attribute, idempotent, capture-safe)
    static int lds_ok = 0;
    (void)hipFuncSetAttribute((const void*)fused_mlp,
                              hipFuncAttributeMaxDynamicSharedMemorySize,
                              LDS_BYTES);
    (void)lds_ok;

    pack_weights<<<(PW1_N + PW2_N + 255) / 256, 256, 0, stream>>>(W1, W2, pw1, pw2);
    fused_mlp<<<BATCH_N / ROWS_PER_BLOCK, 1024, LDS_BYTES, stream>>>(x, b1, b2, pw1, pw2, out);
}